// Round 1
// baseline (1429.013 us; speedup 1.0000x reference)
//
#include <hip/hip_runtime.h>

#define N_NODES 50000
#define N_EDGES 800000
#define DIM 128
#define NGROUPS 64
#define NCLS 32
#define BN_EPS 1e-5f

// ---------------- CSR build ----------------

__global__ void count_kernel(const int* __restrict__ ei, int* __restrict__ cnt, int E) {
    int e = blockIdx.x * 256 + threadIdx.x;
    if (e < E) atomicAdd(&cnt[ei[E + e]], 1);
}

__global__ void scan_kernel(const int* __restrict__ cnt, int* __restrict__ row_start, int n) {
    __shared__ int wsum[16];
    __shared__ int chunk_tot;
    int tid = threadIdx.x, lane = tid & 63, w = tid >> 6;
    int carry = 0;
    for (int base = 0; base < n; base += 1024) {
        int i = base + tid;
        int v = (i < n) ? cnt[i] : 0;
        int x = v;
        #pragma unroll
        for (int off = 1; off < 64; off <<= 1) {
            int t = __shfl_up(x, off);
            if (lane >= off) x += t;
        }
        if (lane == 63) wsum[w] = x;
        __syncthreads();
        if (tid < 16) {
            int ws = wsum[tid], y = ws;
            #pragma unroll
            for (int off = 1; off < 16; off <<= 1) {
                int t = __shfl_up(y, off);
                if (tid >= off) y += t;
            }
            wsum[tid] = y - ws;
            if (tid == 15) chunk_tot = y;
        }
        __syncthreads();
        if (i < n) row_start[i] = carry + wsum[w] + (x - v);
        carry += chunk_tot;
        __syncthreads();
    }
    if (tid == 0) row_start[n] = carry;
}

__global__ void fill_kernel(const int* __restrict__ ei, int* __restrict__ cursor,
                            const int* __restrict__ row_start, int* __restrict__ csr, int E) {
    int e = blockIdx.x * 256 + threadIdx.x;
    if (e >= E) return;
    int dst = ei[E + e];
    int pos = atomicAdd(&cursor[dst], 1);
    csr[row_start[dst] + pos] = ei[e];
}

// group ranges from sorted batch array (handles empty groups)
__global__ void gstart_kernel(const int* __restrict__ batch, int* __restrict__ g_start, int n, int G) {
    int i = blockIdx.x * 256 + threadIdx.x;
    if (i >= n) return;
    int b = batch[i];
    if (i == 0) {
        for (int g = 0; g <= b; ++g) g_start[g] = 0;
    } else {
        int p = batch[i - 1];
        for (int g = p + 1; g <= b; ++g) g_start[g] = i;
    }
    if (i == n - 1) {
        for (int g = b + 1; g <= G; ++g) g_start[g] = n;
    }
}

// ---------------- mean aggregation (gather over CSR) ----------------

__global__ void agg_kernel(const float* __restrict__ xin, const int* __restrict__ csr,
                           const int* __restrict__ row_start, float* __restrict__ out) {
    int node = blockIdx.x;
    int d = threadIdx.x;  // 128
    int s = row_start[node], e = row_start[node + 1];
    float acc = 0.f;
    for (int i = s; i < e; ++i) {
        int src = csr[i];  // block-uniform -> s_load
        acc += xin[src * DIM + d];
    }
    int deg = e - s;
    float inv = 1.f / (float)(deg > 0 ? deg : 1);
    out[node * DIM + d] = acc * inv;
}

// ---------------- dual-matrix linear: out = bias + A@Wa^T (+ B@Wb^T) ----------------
// MODE 0: init with bias; MODE 1: accumulate onto existing out, then ReLU.
// Weights staged transposed in LDS as [k4][d] float4 -> conflict-free ds_read_b128.

template <int NMAT, int MODE>
__global__ __launch_bounds__(256) void linear_kernel(
    const float* __restrict__ A, const float* __restrict__ Wa,
    const float* __restrict__ B, const float* __restrict__ Wb,
    const float* __restrict__ bias, float* __restrict__ out,
    int n_rows, int wstride4) {
    __shared__ float4 WaT[32 * 128];
    __shared__ float4 WbT[32 * 128];
    __shared__ float4 rows[256];  // [0..127]=4 rows of A, [128..255]=4 rows of B
    const float4* A4 = (const float4*)A;
    const float4* B4 = (const float4*)B;
    const float4* Wa4 = (const float4*)Wa;
    const float4* Wb4 = (const float4*)Wb;
    int t = threadIdx.x;
    for (int f = t; f < 4096; f += 256) {
        int d = f >> 5, k4 = f & 31;
        WaT[k4 * 128 + d] = Wa4[d * wstride4 + k4];
        if (NMAT == 2) WbT[k4 * 128 + d] = Wb4[d * wstride4 + k4];
    }
    int d = t & 127;
    int r0 = t >> 7;  // 0..1, each thread does rows r0 and r0+2
    float bias_d = (MODE == 0) ? bias[d] : 0.f;
    int num_iters = (n_rows + 3) >> 2;
    const float4 f4z = {0.f, 0.f, 0.f, 0.f};
    float4 stage = f4z;
    int it = blockIdx.x;
    {
        int rr = (t & 127) >> 5, k4 = t & 31;
        int row = it * 4 + rr;
        if (t < 128) stage = (it < num_iters && row < n_rows) ? A4[row * 32 + k4] : f4z;
        else if (NMAT == 2) stage = (it < num_iters && row < n_rows) ? B4[row * 32 + k4] : f4z;
    }
    __syncthreads();  // WaT/WbT ready
    for (; it < num_iters; it += gridDim.x) {
        if (t < 128 || NMAT == 2) rows[t] = stage;
        __syncthreads();
        {   // prefetch next assigned iteration's rows into registers
            int nit = it + gridDim.x;
            int rr = (t & 127) >> 5, k4 = t & 31;
            int row = nit * 4 + rr;
            if (t < 128) stage = (nit < num_iters && row < n_rows) ? A4[row * 32 + k4] : f4z;
            else if (NMAT == 2) stage = (nit < num_iters && row < n_rows) ? B4[row * 32 + k4] : f4z;
        }
        int row0 = it * 4 + r0, row1 = row0 + 2;
        float acc0, acc1;
        if (MODE == 0) {
            acc0 = bias_d; acc1 = bias_d;
        } else {
            acc0 = (row0 < n_rows) ? out[row0 * DIM + d] : 0.f;
            acc1 = (row1 < n_rows) ? out[row1 * DIM + d] : 0.f;
        }
        #pragma unroll 8
        for (int k4 = 0; k4 < 32; ++k4) {
            float4 wa = WaT[k4 * 128 + d];
            float4 a0 = rows[r0 * 32 + k4];
            float4 a1 = rows[(r0 + 2) * 32 + k4];
            acc0 += wa.x * a0.x + wa.y * a0.y + wa.z * a0.z + wa.w * a0.w;
            acc1 += wa.x * a1.x + wa.y * a1.y + wa.z * a1.z + wa.w * a1.w;
            if (NMAT == 2) {
                float4 wb = WbT[k4 * 128 + d];
                float4 b0 = rows[128 + r0 * 32 + k4];
                float4 b1 = rows[128 + (r0 + 2) * 32 + k4];
                acc0 += wb.x * b0.x + wb.y * b0.y + wb.z * b0.z + wb.w * b0.w;
                acc1 += wb.x * b1.x + wb.y * b1.y + wb.z * b1.z + wb.w * b1.w;
            }
        }
        if (MODE == 1) { acc0 = fmaxf(acc0, 0.f); acc1 = fmaxf(acc1, 0.f); }
        if (row0 < n_rows) out[row0 * DIM + d] = acc0;
        if (row1 < n_rows) out[row1 * DIM + d] = acc1;
        __syncthreads();
    }
}

// ---------------- BatchNorm (train-mode) + PReLU ----------------

__global__ void bn_stats_kernel(const float* __restrict__ y, float* __restrict__ sums, int n) {
    const float4* y4 = (const float4*)y;
    int t = threadIdx.x, d4 = t & 31, rg = t >> 5;
    float4 s = {0, 0, 0, 0}, q = {0, 0, 0, 0};
    for (int row = blockIdx.x * 8 + rg; row < n; row += gridDim.x * 8) {
        float4 v = y4[row * 32 + d4];
        s.x += v.x; s.y += v.y; s.z += v.z; s.w += v.w;
        q.x += v.x * v.x; q.y += v.y * v.y; q.z += v.z * v.z; q.w += v.w * v.w;
    }
    __shared__ float4 sh[256], sh2[256];
    sh[t] = s; sh2[t] = q;
    __syncthreads();
    if (rg == 0) {
        for (int j = 1; j < 8; ++j) {
            float4 a = sh[j * 32 + d4], b2 = sh2[j * 32 + d4];
            s.x += a.x; s.y += a.y; s.z += a.z; s.w += a.w;
            q.x += b2.x; q.y += b2.y; q.z += b2.z; q.w += b2.w;
        }
        atomicAdd(&sums[d4 * 4 + 0], s.x); atomicAdd(&sums[d4 * 4 + 1], s.y);
        atomicAdd(&sums[d4 * 4 + 2], s.z); atomicAdd(&sums[d4 * 4 + 3], s.w);
        atomicAdd(&sums[128 + d4 * 4 + 0], q.x); atomicAdd(&sums[128 + d4 * 4 + 1], q.y);
        atomicAdd(&sums[128 + d4 * 4 + 2], q.z); atomicAdd(&sums[128 + d4 * 4 + 3], q.w);
    }
}

__global__ void bn_coef_kernel(const float* __restrict__ sums, const float* __restrict__ g,
                               const float* __restrict__ b, float* __restrict__ coef, float invn) {
    int d = threadIdx.x;  // 128
    float m = sums[d] * invn;
    float var = sums[128 + d] * invn - m * m;
    float sc = g[d] * rsqrtf(var + BN_EPS);
    coef[d] = sc;
    coef[128 + d] = b[d] - m * sc;
}

__global__ void bn_apply_kernel(const float* __restrict__ y, const float* __restrict__ coef,
                                const float* __restrict__ a, float* __restrict__ xout, int n) {
    int idx = blockIdx.x * blockDim.x + threadIdx.x;
    int total = n * 32;
    float alpha = a[0];
    const float4* y4 = (const float4*)y;
    const float4* c4 = (const float4*)coef;
    float4* o4 = (float4*)xout;
    for (; idx < total; idx += gridDim.x * blockDim.x) {
        int d4 = idx & 31;
        float4 v = y4[idx];
        float4 sc = c4[d4], sf = c4[32 + d4];
        float4 r;
        r.x = v.x * sc.x + sf.x; r.y = v.y * sc.y + sf.y;
        r.z = v.z * sc.z + sf.z; r.w = v.w * sc.w + sf.w;
        r.x = r.x >= 0.f ? r.x : alpha * r.x;
        r.y = r.y >= 0.f ? r.y : alpha * r.y;
        r.z = r.z >= 0.f ? r.z : alpha * r.z;
        r.w = r.w >= 0.f ? r.w : alpha * r.w;
        o4[idx] = r;
    }
}

// ---------------- pooling + classifier ----------------

__global__ void pool_kernel(const float* __restrict__ h, const int* __restrict__ g_start,
                            float* __restrict__ pooled) {
    int g = blockIdx.x >> 3, part = blockIdx.x & 7;
    int d = threadIdx.x;  // 128
    int s = g_start[g], e = g_start[g + 1];
    int len = e - s;
    int ps = s + ((len * part) >> 3), pe = s + ((len * (part + 1)) >> 3);
    float acc = 0.f;
    for (int i = ps; i < pe; ++i) acc += h[i * DIM + d];
    atomicAdd(&pooled[g * DIM + d], acc);
}

__global__ void final_kernel(const float* __restrict__ pooled, const int* __restrict__ g_start,
                             const float* __restrict__ Wf, const float* __restrict__ bf,
                             float* __restrict__ out) {
    int idx = blockIdx.x * 256 + threadIdx.x;  // 2048 = 64 groups x 32 classes
    int g = idx >> 5, c = idx & 31;
    int cnt = g_start[g + 1] - g_start[g];
    float inv = 1.f / (float)(cnt > 0 ? cnt : 1);
    float acc = 0.f;
    for (int dd = 0; dd < 128; ++dd) acc += pooled[g * DIM + dd] * Wf[c * DIM + dd];
    out[idx] = acc * inv + bf[c];
}

// ---------------- launcher ----------------

extern "C" void kernel_launch(void* const* d_in, const int* in_sizes, int n_in,
                              void* d_out, int out_size, void* d_ws, size_t ws_size,
                              hipStream_t stream) {
    const float* x = (const float*)d_in[0];
    const int* ei = (const int*)d_in[1];
    const int* batch = (const int*)d_in[2];
    const float* Wl[3] = {(const float*)d_in[3], (const float*)d_in[9], (const float*)d_in[15]};
    const float* bl[3] = {(const float*)d_in[4], (const float*)d_in[10], (const float*)d_in[16]};
    const float* Wr[3] = {(const float*)d_in[5], (const float*)d_in[11], (const float*)d_in[17]};
    const float* gg[3] = {(const float*)d_in[6], (const float*)d_in[12], (const float*)d_in[18]};
    const float* bb[3] = {(const float*)d_in[7], (const float*)d_in[13], (const float*)d_in[19]};
    const float* aa[3] = {(const float*)d_in[8], (const float*)d_in[14], (const float*)d_in[20]};
    const float* Wjk = (const float*)d_in[21];
    const float* bjk = (const float*)d_in[22];
    const float* Wf = (const float*)d_in[23];
    const float* bf = (const float*)d_in[24];
    float* out = (float*)d_out;

    char* ws = (char*)d_ws;
    size_t off = 0;
    auto alloc = [&](size_t bytes) {
        void* p = ws + off;
        off += (bytes + 255) & ~(size_t)255;
        return p;
    };
    int* row_start = (int*)alloc((N_NODES + 1) * 4);
    int* cnt = (int*)alloc(N_NODES * 4);
    int* cursor = (int*)alloc(N_NODES * 4);
    int* csr = (int*)alloc((size_t)N_EDGES * 4);
    int* g_start = (int*)alloc((NGROUPS + 1) * 4);
    float* bn_sums = (float*)alloc(256 * 4);
    float* bn_coef = (float*)alloc(256 * 4);
    float* pooled = (float*)alloc(NGROUPS * DIM * 4);
    float* X1 = (float*)alloc((size_t)N_NODES * DIM * 4);
    float* X2 = (float*)alloc((size_t)N_NODES * DIM * 4);
    float* X3 = (float*)alloc((size_t)N_NODES * DIM * 4);
    float* AGG = (float*)alloc((size_t)N_NODES * DIM * 4);
    float* Xl[3] = {X1, X2, X3};

    hipMemsetAsync(cnt, 0, N_NODES * 4, stream);
    hipMemsetAsync(cursor, 0, N_NODES * 4, stream);
    hipMemsetAsync(pooled, 0, NGROUPS * DIM * 4, stream);

    count_kernel<<<(N_EDGES + 255) / 256, 256, 0, stream>>>(ei, cnt, N_EDGES);
    scan_kernel<<<1, 1024, 0, stream>>>(cnt, row_start, N_NODES);
    fill_kernel<<<(N_EDGES + 255) / 256, 256, 0, stream>>>(ei, cursor, row_start, csr, N_EDGES);
    gstart_kernel<<<(N_NODES + 255) / 256, 256, 0, stream>>>(batch, g_start, N_NODES, NGROUPS);

    const float* xin = x;
    for (int l = 0; l < 3; ++l) {
        agg_kernel<<<N_NODES, 128, 0, stream>>>(xin, csr, row_start, AGG);
        linear_kernel<2, 0><<<256, 256, 0, stream>>>(AGG, Wl[l], xin, Wr[l], bl[l], AGG, N_NODES, 32);
        hipMemsetAsync(bn_sums, 0, 256 * 4, stream);
        bn_stats_kernel<<<256, 256, 0, stream>>>(AGG, bn_sums, N_NODES);
        bn_coef_kernel<<<1, 128, 0, stream>>>(bn_sums, gg[l], bb[l], bn_coef, 1.f / N_NODES);
        bn_apply_kernel<<<2048, 256, 0, stream>>>(AGG, bn_coef, aa[l], Xl[l], N_NODES);
        xin = Xl[l];
    }

    // JK: h = relu(X1@W1^T + X2@W2^T + X3@W3^T + bjk), Wi = column blocks of Wjk [128][384]
    linear_kernel<2, 0><<<256, 256, 0, stream>>>(X1, Wjk, X2, Wjk + 128, bjk, AGG, N_NODES, 96);
    linear_kernel<1, 1><<<256, 256, 0, stream>>>(X3, Wjk + 256, nullptr, nullptr, nullptr, AGG, N_NODES, 96);

    pool_kernel<<<NGROUPS * 8, 128, 0, stream>>>(AGG, g_start, pooled);
    final_kernel<<<8, 256, 0, stream>>>(pooled, g_start, Wf, bf, out);
}

// Round 2
// 681.151 us; speedup vs baseline: 2.0979x; 2.0979x over previous
//
#include <hip/hip_runtime.h>

#define N_NODES 50000
#define N_EDGES 800000
#define DIM 128
#define NGROUPS 64
#define NCLS 32
#define BN_EPS 1e-5f

typedef short short8_t __attribute__((ext_vector_type(8)));
typedef float f32x4 __attribute__((ext_vector_type(4)));
typedef const __attribute__((address_space(1))) unsigned char* gptr_t;
typedef __attribute__((address_space(3))) unsigned char* sptr_t;

__device__ __forceinline__ unsigned short f2bf(float f) {
    unsigned int u = __float_as_uint(f);
    u += 0x7FFFu + ((u >> 16) & 1u);   // round-to-nearest-even
    return (unsigned short)(u >> 16);
}

// ---------------- CSR build ----------------

__global__ void count_kernel(const int* __restrict__ ei, int* __restrict__ cnt, int E) {
    int e = blockIdx.x * 256 + threadIdx.x;
    if (e < E) atomicAdd(&cnt[ei[E + e]], 1);
}

__global__ void scan_kernel(const int* __restrict__ cnt, int* __restrict__ row_start, int n) {
    __shared__ int wsum[16];
    __shared__ int chunk_tot;
    int tid = threadIdx.x, lane = tid & 63, w = tid >> 6;
    int carry = 0;
    for (int base = 0; base < n; base += 1024) {
        int i = base + tid;
        int v = (i < n) ? cnt[i] : 0;
        int x = v;
        #pragma unroll
        for (int off = 1; off < 64; off <<= 1) {
            int t = __shfl_up(x, off);
            if (lane >= off) x += t;
        }
        if (lane == 63) wsum[w] = x;
        __syncthreads();
        if (tid < 16) {
            int ws = wsum[tid], y = ws;
            #pragma unroll
            for (int off = 1; off < 16; off <<= 1) {
                int t = __shfl_up(y, off);
                if (tid >= off) y += t;
            }
            wsum[tid] = y - ws;
            if (tid == 15) chunk_tot = y;
        }
        __syncthreads();
        if (i < n) row_start[i] = carry + wsum[w] + (x - v);
        carry += chunk_tot;
        __syncthreads();
    }
    if (tid == 0) row_start[n] = carry;
}

__global__ void fill_kernel(const int* __restrict__ ei, int* __restrict__ cursor,
                            const int* __restrict__ row_start, int* __restrict__ csr, int E) {
    int e = blockIdx.x * 256 + threadIdx.x;
    if (e >= E) return;
    int dst = ei[E + e];
    int pos = atomicAdd(&cursor[dst], 1);
    csr[row_start[dst] + pos] = ei[e];
}

__global__ void gstart_kernel(const int* __restrict__ batch, int* __restrict__ g_start, int n, int G) {
    int i = blockIdx.x * 256 + threadIdx.x;
    if (i >= n) return;
    int b = batch[i];
    if (i == 0) {
        for (int g = 0; g <= b; ++g) g_start[g] = 0;
    } else {
        int p = batch[i - 1];
        for (int g = p + 1; g <= b; ++g) g_start[g] = i;
    }
    if (i == n - 1) {
        for (int g = b + 1; g <= G; ++g) g_start[g] = n;
    }
}

// ---------------- dtype conversion ----------------

__global__ void convert_x_kernel(const float* __restrict__ src, unsigned int* __restrict__ dst, int total4) {
    // total4 = N*DIM/4 ; each iter handles 4 floats -> 4 bf16 (2 uints)
    const float4* s4 = (const float4*)src;
    for (int idx = blockIdx.x * blockDim.x + threadIdx.x; idx < total4; idx += gridDim.x * blockDim.x) {
        float4 v = s4[idx];
        unsigned int lo = (unsigned int)f2bf(v.x) | ((unsigned int)f2bf(v.y) << 16);
        unsigned int hi = (unsigned int)f2bf(v.z) | ((unsigned int)f2bf(v.w) << 16);
        dst[idx * 2] = lo;
        dst[idx * 2 + 1] = hi;
    }
}

// six 128x128 weight matrices, flat copy
__global__ void convert_w6_kernel(const float* s0, const float* s1, const float* s2,
                                  const float* s3, const float* s4, const float* s5,
                                  unsigned short* __restrict__ dst) {
    int idx = blockIdx.x * 256 + threadIdx.x;   // 0 .. 6*16384
    int mat = idx >> 14, off = idx & 16383;
    const float* s = (mat == 0) ? s0 : (mat == 1) ? s1 : (mat == 2) ? s2
                   : (mat == 3) ? s3 : (mat == 4) ? s4 : s5;
    dst[idx] = f2bf(s[off]);
}

// Wjk [128][384] -> three [128][128] bf16 mats
__global__ void convert_wjk_kernel(const float* __restrict__ src, unsigned short* __restrict__ dst) {
    int idx = blockIdx.x * 256 + threadIdx.x;   // 0 .. 49152
    int d = idx / 384, k = idx - d * 384;
    int part = k >> 7, kk = k & 127;
    dst[part * 16384 + d * 128 + kk] = f2bf(src[idx]);
}

// ---------------- mean aggregation (bf16 gather over CSR) ----------------

__global__ void agg_kernel(const unsigned short* __restrict__ xin, const int* __restrict__ csr,
                           const int* __restrict__ row_start, unsigned short* __restrict__ out) {
    int node = blockIdx.x * 4 + (threadIdx.x >> 6);
    int lane = threadIdx.x & 63;
    const unsigned int* base = (const unsigned int*)xin;   // 2 bf16 per uint
    int s = row_start[node], e = row_start[node + 1];
    float a0 = 0.f, a1 = 0.f;
    int i = s;
    for (; i + 1 < e; i += 2) {
        int s0 = csr[i], s1 = csr[i + 1];
        unsigned int u0 = base[s0 * 64 + lane];
        unsigned int u1 = base[s1 * 64 + lane];
        a0 += __uint_as_float(u0 << 16) + __uint_as_float(u1 << 16);
        a1 += __uint_as_float(u0 & 0xffff0000u) + __uint_as_float(u1 & 0xffff0000u);
    }
    if (i < e) {
        unsigned int u0 = base[csr[i] * 64 + lane];
        a0 += __uint_as_float(u0 << 16);
        a1 += __uint_as_float(u0 & 0xffff0000u);
    }
    int deg = e - s;
    float inv = 1.f / (float)(deg > 0 ? deg : 1);
    a0 *= inv; a1 *= inv;
    unsigned int packed = (unsigned int)f2bf(a0) | ((unsigned int)f2bf(a1) << 16);
    ((unsigned int*)out)[node * 64 + lane] = packed;
}

// ---------------- MFMA linear: C = sum_p A_p @ W_p^T (+bias | +=C, relu) ----------------
// P parts of K=128 each. A_p: [n][128] bf16. W_p: [128][128] bf16 (row = out col, k contiguous).
// MODE 0: C = sum + bias.  MODE 1: C = relu(C + sum).
// Block: 128 rows x 128 cols, 4 waves 2x2 (wave = 64 rows x 64 cols, 4x4 frags of 16x16x32).
// Activations staged to LDS via global_load_lds with pre-swizzled source (conflict-free reads);
// weights live entirely in registers (P*16 frags).

template <int P, int MODE>
__global__ __launch_bounds__(256, 2) void mfma_linear(
    const unsigned short* __restrict__ A0, const unsigned short* __restrict__ A1,
    const unsigned short* __restrict__ W0, const unsigned short* __restrict__ W1,
    const float* __restrict__ bias, float* __restrict__ C, int n_rows) {
    constexpr int KS = P * 4;          // k-steps of 32
    constexpr int S = P * 16;          // 16B slots per LDS row
    __shared__ char lds[128 * P * 256];  // 128 rows x P*256 bytes
    int t = threadIdx.x;
    int lane = t & 63;
    int wr = (t >> 7) & 1, wc = (t >> 6) & 1;   // wave (row, col) in 2x2
    int row_base = blockIdx.x * 128;

    // ---- stage activations: LDS linear dest, swizzled global source
    #pragma unroll
    for (int c = 0; c < (128 * S) / 256; ++c) {
        int flat = c * 256 + t;
        int row = flat / S;
        int s = flat & (S - 1);
        int ss = s ^ (row & 7);                 // pre-swizzle source slot
        int grow = row_base + row;
        if (grow >= n_rows) grow = n_rows - 1;  // clamp: garbage rows never stored
        const unsigned short* srcp;
        if (P == 2) srcp = (ss < 16) ? (A0 + (size_t)grow * 128 + ss * 8)
                                     : (A1 + (size_t)grow * 128 + (ss - 16) * 8);
        else        srcp = A0 + (size_t)grow * 128 + ss * 8;
        __builtin_amdgcn_global_load_lds((gptr_t)srcp, (sptr_t)(lds + flat * 16), 16, 0, 0);
    }

    // ---- weight fragments -> registers (reused for whole block)
    short8_t bfrag[KS][4];
    #pragma unroll
    for (int ks = 0; ks < KS; ++ks) {
        const unsigned short* Wp = (P == 2 && ks >= 4) ? W1 : W0;
        int ksp = ks & 3;
        #pragma unroll
        for (int nn = 0; nn < 4; ++nn) {
            int col = wc * 64 + nn * 16 + (lane & 15);
            int k0 = ksp * 32 + (lane >> 4) * 8;
            bfrag[ks][nn] = *(const short8_t*)(Wp + col * 128 + k0);
        }
    }

    f32x4 acc[4][4];
    #pragma unroll
    for (int m = 0; m < 4; ++m)
        #pragma unroll
        for (int nn = 0; nn < 4; ++nn)
            acc[m][nn] = (f32x4){0.f, 0.f, 0.f, 0.f};

    __syncthreads();   // drains vmcnt (global_load_lds) before ds_read

    // ---- main loop
    #pragma unroll
    for (int ks = 0; ks < KS; ++ks) {
        short8_t a[4];
        #pragma unroll
        for (int m = 0; m < 4; ++m) {
            int row = wr * 64 + m * 16 + (lane & 15);
            int s = ks * 4 + (lane >> 4);
            int off = row * (P * 256) + ((s ^ (row & 7)) * 16);
            a[m] = *(const short8_t*)(lds + off);
        }
        #pragma unroll
        for (int m = 0; m < 4; ++m)
            #pragma unroll
            for (int nn = 0; nn < 4; ++nn)
                acc[m][nn] = __builtin_amdgcn_mfma_f32_16x16x32_bf16(a[m], bfrag[ks][nn], acc[m][nn], 0, 0, 0);
    }

    // ---- epilogue
    #pragma unroll
    for (int nn = 0; nn < 4; ++nn) {
        int col = wc * 64 + nn * 16 + (lane & 15);
        float badd = (MODE == 0) ? bias[col] : 0.f;
        #pragma unroll
        for (int m = 0; m < 4; ++m) {
            #pragma unroll
            for (int j = 0; j < 4; ++j) {
                int row = row_base + wr * 64 + m * 16 + (lane >> 4) * 4 + j;
                if (row < n_rows) {
                    float v = acc[m][nn][j];
                    if (MODE == 0) {
                        v += badd;
                    } else {
                        v += C[(size_t)row * 128 + col];
                        v = fmaxf(v, 0.f);
                    }
                    C[(size_t)row * 128 + col] = v;
                }
            }
        }
    }
}

// ---------------- BatchNorm (train-mode) + PReLU ----------------

__global__ void bn_stats_kernel(const float* __restrict__ y, float* __restrict__ sums, int n) {
    const float4* y4 = (const float4*)y;
    int t = threadIdx.x, d4 = t & 31, rg = t >> 5;
    float4 s = {0, 0, 0, 0}, q = {0, 0, 0, 0};
    for (int row = blockIdx.x * 8 + rg; row < n; row += gridDim.x * 8) {
        float4 v = y4[row * 32 + d4];
        s.x += v.x; s.y += v.y; s.z += v.z; s.w += v.w;
        q.x += v.x * v.x; q.y += v.y * v.y; q.z += v.z * v.z; q.w += v.w * v.w;
    }
    __shared__ float4 sh[256], sh2[256];
    sh[t] = s; sh2[t] = q;
    __syncthreads();
    if (rg == 0) {
        for (int j = 1; j < 8; ++j) {
            float4 a = sh[j * 32 + d4], b2 = sh2[j * 32 + d4];
            s.x += a.x; s.y += a.y; s.z += a.z; s.w += a.w;
            q.x += b2.x; q.y += b2.y; q.z += b2.z; q.w += b2.w;
        }
        atomicAdd(&sums[d4 * 4 + 0], s.x); atomicAdd(&sums[d4 * 4 + 1], s.y);
        atomicAdd(&sums[d4 * 4 + 2], s.z); atomicAdd(&sums[d4 * 4 + 3], s.w);
        atomicAdd(&sums[128 + d4 * 4 + 0], q.x); atomicAdd(&sums[128 + d4 * 4 + 1], q.y);
        atomicAdd(&sums[128 + d4 * 4 + 2], q.z); atomicAdd(&sums[128 + d4 * 4 + 3], q.w);
    }
}

__global__ void bn_coef_kernel(const float* __restrict__ sums, const float* __restrict__ g,
                               const float* __restrict__ b, float* __restrict__ coef, float invn) {
    int d = threadIdx.x;  // 128
    float m = sums[d] * invn;
    float var = sums[128 + d] * invn - m * m;
    float sc = g[d] * rsqrtf(var + BN_EPS);
    coef[d] = sc;
    coef[128 + d] = b[d] - m * sc;
}

// reads fp32 Y, writes bf16 X
__global__ void bn_apply_kernel(const float* __restrict__ y, const float* __restrict__ coef,
                                const float* __restrict__ a, unsigned int* __restrict__ xout, int n) {
    int idx = blockIdx.x * blockDim.x + threadIdx.x;
    int total = n * 32;
    float alpha = a[0];
    const float4* y4 = (const float4*)y;
    const float4* c4 = (const float4*)coef;
    for (; idx < total; idx += gridDim.x * blockDim.x) {
        int d4 = idx & 31;
        float4 v = y4[idx];
        float4 sc = c4[d4], sf = c4[32 + d4];
        float4 r;
        r.x = v.x * sc.x + sf.x; r.y = v.y * sc.y + sf.y;
        r.z = v.z * sc.z + sf.z; r.w = v.w * sc.w + sf.w;
        r.x = r.x >= 0.f ? r.x : alpha * r.x;
        r.y = r.y >= 0.f ? r.y : alpha * r.y;
        r.z = r.z >= 0.f ? r.z : alpha * r.z;
        r.w = r.w >= 0.f ? r.w : alpha * r.w;
        xout[idx * 2] = (unsigned int)f2bf(r.x) | ((unsigned int)f2bf(r.y) << 16);
        xout[idx * 2 + 1] = (unsigned int)f2bf(r.z) | ((unsigned int)f2bf(r.w) << 16);
    }
}

// ---------------- pooling + classifier ----------------

__global__ void pool_kernel(const float* __restrict__ h, const int* __restrict__ g_start,
                            float* __restrict__ pooled) {
    int g = blockIdx.x >> 3, part = blockIdx.x & 7;
    int d = threadIdx.x;  // 128
    int s = g_start[g], e = g_start[g + 1];
    int len = e - s;
    int ps = s + ((len * part) >> 3), pe = s + ((len * (part + 1)) >> 3);
    float acc = 0.f;
    for (int i = ps; i < pe; ++i) acc += h[i * DIM + d];
    atomicAdd(&pooled[g * DIM + d], acc);
}

__global__ void final_kernel(const float* __restrict__ pooled, const int* __restrict__ g_start,
                             const float* __restrict__ Wf, const float* __restrict__ bf,
                             float* __restrict__ out) {
    int idx = blockIdx.x * 256 + threadIdx.x;  // 2048 = 64 groups x 32 classes
    int g = idx >> 5, c = idx & 31;
    int cnt = g_start[g + 1] - g_start[g];
    float inv = 1.f / (float)(cnt > 0 ? cnt : 1);
    float acc = 0.f;
    for (int dd = 0; dd < 128; ++dd) acc += pooled[g * DIM + dd] * Wf[c * DIM + dd];
    out[idx] = acc * inv + bf[c];
}

// ---------------- launcher ----------------

extern "C" void kernel_launch(void* const* d_in, const int* in_sizes, int n_in,
                              void* d_out, int out_size, void* d_ws, size_t ws_size,
                              hipStream_t stream) {
    const float* x = (const float*)d_in[0];
    const int* ei = (const int*)d_in[1];
    const int* batch = (const int*)d_in[2];
    const float* Wl[3] = {(const float*)d_in[3], (const float*)d_in[9], (const float*)d_in[15]};
    const float* bl[3] = {(const float*)d_in[4], (const float*)d_in[10], (const float*)d_in[16]};
    const float* Wr[3] = {(const float*)d_in[5], (const float*)d_in[11], (const float*)d_in[17]};
    const float* gg[3] = {(const float*)d_in[6], (const float*)d_in[12], (const float*)d_in[18]};
    const float* bb[3] = {(const float*)d_in[7], (const float*)d_in[13], (const float*)d_in[19]};
    const float* aa[3] = {(const float*)d_in[8], (const float*)d_in[14], (const float*)d_in[20]};
    const float* Wjk = (const float*)d_in[21];
    const float* bjk = (const float*)d_in[22];
    const float* Wf = (const float*)d_in[23];
    const float* bf = (const float*)d_in[24];
    float* out = (float*)d_out;

    char* ws = (char*)d_ws;
    size_t off = 0;
    auto alloc = [&](size_t bytes) {
        void* p = ws + off;
        off += (bytes + 255) & ~(size_t)255;
        return p;
    };
    int* row_start = (int*)alloc((N_NODES + 1) * 4);
    int* cnt = (int*)alloc(N_NODES * 4);
    int* cursor = (int*)alloc(N_NODES * 4);
    int* csr = (int*)alloc((size_t)N_EDGES * 4);
    int* g_start = (int*)alloc((NGROUPS + 1) * 4);
    float* bn_sums = (float*)alloc(256 * 4);
    float* bn_coef = (float*)alloc(256 * 4);
    float* pooled = (float*)alloc(NGROUPS * DIM * 4);
    float* Y = (float*)alloc((size_t)N_NODES * DIM * 4);            // fp32 GEMM out / JK out
    unsigned short* X0 = (unsigned short*)alloc((size_t)N_NODES * DIM * 2);
    unsigned short* X1 = (unsigned short*)alloc((size_t)N_NODES * DIM * 2);
    unsigned short* X2 = (unsigned short*)alloc((size_t)N_NODES * DIM * 2);
    unsigned short* X3 = (unsigned short*)alloc((size_t)N_NODES * DIM * 2);
    unsigned short* AGGb = (unsigned short*)alloc((size_t)N_NODES * DIM * 2);
    unsigned short* Wb = (unsigned short*)alloc((size_t)9 * 16384 * 2);  // 6 layer mats + 3 JK mats
    unsigned short* Wlb[3] = {Wb, Wb + 2 * 16384, Wb + 4 * 16384};
    unsigned short* Wrb[3] = {Wb + 16384, Wb + 3 * 16384, Wb + 5 * 16384};
    unsigned short* Wjkb = Wb + 6 * 16384;
    unsigned short* Xl[3] = {X1, X2, X3};

    hipMemsetAsync(cnt, 0, N_NODES * 4, stream);
    hipMemsetAsync(cursor, 0, N_NODES * 4, stream);
    hipMemsetAsync(pooled, 0, NGROUPS * DIM * 4, stream);

    count_kernel<<<(N_EDGES + 255) / 256, 256, 0, stream>>>(ei, cnt, N_EDGES);
    scan_kernel<<<1, 1024, 0, stream>>>(cnt, row_start, N_NODES);
    fill_kernel<<<(N_EDGES + 255) / 256, 256, 0, stream>>>(ei, cursor, row_start, csr, N_EDGES);
    gstart_kernel<<<(N_NODES + 255) / 256, 256, 0, stream>>>(batch, g_start, N_NODES, NGROUPS);

    convert_x_kernel<<<2048, 256, 0, stream>>>(x, (unsigned int*)X0, N_NODES * 32);
    convert_w6_kernel<<<384, 256, 0, stream>>>(Wl[0], Wr[0], Wl[1], Wr[1], Wl[2], Wr[2], Wb);
    convert_wjk_kernel<<<192, 256, 0, stream>>>(Wjk, Wjkb);

    const int NBLK = (N_NODES + 127) / 128;  // 391
    const unsigned short* xin = X0;
    for (int l = 0; l < 3; ++l) {
        agg_kernel<<<N_NODES / 4, 256, 0, stream>>>(xin, csr, row_start, AGGb);
        mfma_linear<2, 0><<<NBLK, 256, 0, stream>>>(AGGb, xin, Wlb[l], Wrb[l], bl[l], Y, N_NODES);
        hipMemsetAsync(bn_sums, 0, 256 * 4, stream);
        bn_stats_kernel<<<256, 256, 0, stream>>>(Y, bn_sums, N_NODES);
        bn_coef_kernel<<<1, 128, 0, stream>>>(bn_sums, gg[l], bb[l], bn_coef, 1.f / N_NODES);
        bn_apply_kernel<<<2048, 256, 0, stream>>>(Y, bn_coef, aa[l], (unsigned int*)Xl[l], N_NODES);
        xin = Xl[l];
    }

    // JK: H = relu(X1@Wjk0^T + X2@Wjk1^T + X3@Wjk2^T + bjk)  (into Y)
    mfma_linear<2, 0><<<NBLK, 256, 0, stream>>>(X1, X2, Wjkb, Wjkb + 16384, bjk, Y, N_NODES);
    mfma_linear<1, 1><<<NBLK, 256, 0, stream>>>(X3, nullptr, Wjkb + 2 * 16384, nullptr, nullptr, Y, N_NODES);

    pool_kernel<<<NGROUPS * 8, 128, 0, stream>>>(Y, g_start, pooled);
    final_kernel<<<8, 256, 0, stream>>>(pooled, g_start, Wf, bf, out);
}